// Round 1
// baseline (734.823 us; speedup 1.0000x reference)
//
#include <hip/hip_runtime.h>
#include <math.h>

#define T 2048
#define HID 4096
#define NH 32
#define NKV 8
#define HD 128
#define QSCALE 0.08838834764831845f   // 1/sqrt(128)

typedef __attribute__((ext_vector_type(8))) short short8;
typedef __attribute__((ext_vector_type(4))) float f32x4;

static __device__ __forceinline__ unsigned short f2bf(float f) {
  union { float f; unsigned u; } v; v.f = f;
  unsigned r = v.u;
  r += 0x7fffu + ((r >> 16) & 1u);   // round-to-nearest-even
  return (unsigned short)(r >> 16);
}

// ---------------- cast fp32 -> bf16 (vectorized x4) ----------------
__global__ __launch_bounds__(256) void cast_bf16_kernel(const float* __restrict__ src,
                                                        unsigned short* __restrict__ dst,
                                                        int n4) {
  int i = blockIdx.x * 256 + threadIdx.x;
  if (i >= n4) return;
  float4 f = ((const float4*)src)[i];
  ushort4 o;
  o.x = f2bf(f.x); o.y = f2bf(f.y); o.z = f2bf(f.z); o.w = f2bf(f.w);
  ((ushort4*)dst)[i] = o;
}

// ---------------- GEMM: C[M,N] fp32 = A[M,K]bf16 * Bt[N,K]bf16^T ----------------
// 128x128 tile, BK=64, 4 waves (2x2), each wave 64x64 via 4x4 of 16x16x32 MFMA.
__global__ __launch_bounds__(256) void gemm_bt(const unsigned short* __restrict__ A,
                                               const unsigned short* __restrict__ Bt,
                                               float* __restrict__ C,
                                               int M, int N, int K) {
  __shared__ __align__(16) unsigned short As[128][72];  // +8 pad: balanced bank groups
  __shared__ __align__(16) unsigned short Bs[128][72];
  int tid = threadIdx.x;
  int wave = tid >> 6, lane = tid & 63;
  int lm = lane & 15, q4 = lane >> 4;
  int wr = (wave >> 1) * 64, wc = (wave & 1) * 64;
  long bm0 = (long)blockIdx.y * 128, bn0 = (long)blockIdx.x * 128;

  f32x4 acc[4][4] = {};
  for (int k0 = 0; k0 < K; k0 += 64) {
#pragma unroll
    for (int i = 0; i < 4; i++) {
      int t = tid + i * 256;           // 1024 chunks of 8 elems = 128x64
      int row = t >> 3, col8 = (t & 7) * 8;
      *(short8*)&As[row][col8] = *(const short8*)&A[(bm0 + row) * (long)K + k0 + col8];
      *(short8*)&Bs[row][col8] = *(const short8*)&Bt[(bn0 + row) * (long)K + k0 + col8];
    }
    __syncthreads();
#pragma unroll
    for (int kk = 0; kk < 2; kk++) {
      short8 af[4], bfr[4];
#pragma unroll
      for (int i = 0; i < 4; i++) af[i]  = *(const short8*)&As[wr + i * 16 + lm][kk * 32 + q4 * 8];
#pragma unroll
      for (int j = 0; j < 4; j++) bfr[j] = *(const short8*)&Bs[wc + j * 16 + lm][kk * 32 + q4 * 8];
#pragma unroll
      for (int i = 0; i < 4; i++)
#pragma unroll
        for (int j = 0; j < 4; j++)
          acc[i][j] = __builtin_amdgcn_mfma_f32_16x16x32_bf16(af[i], bfr[j], acc[i][j], 0, 0, 0);
    }
    __syncthreads();
  }
#pragma unroll
  for (int i = 0; i < 4; i++)
#pragma unroll
    for (int j = 0; j < 4; j++)
#pragma unroll
      for (int r = 0; r < 4; r++)
        C[(bm0 + wr + i * 16 + q4 * 4 + r) * (long)N + bn0 + wc + j * 16 + lm] = acc[i][j][r];
}

// ---------------- RoPE (llama3 scaling) on Q,K; writes head-major bf16 ----------------
// grid (T, NH+NKV), block 64. Q gets 1/sqrt(D) folded in.
__global__ __launch_bounds__(64) void rope_qk(const float* __restrict__ qf,
                                              const float* __restrict__ kf,
                                              unsigned short* __restrict__ qb,
                                              unsigned short* __restrict__ kb) {
  int t = blockIdx.x, hh = blockIdx.y, d = threadIdx.x;  // d in [0,64)
  float ex = (float)d * (1.0f / 64.0f);
  float inv = expf(-ex * 13.122363377404328f);           // 500000^(-d/64)
  float wl = 6.283185307179586f / inv;
  float inv_s;
  if (wl > 8192.0f)       inv_s = inv * 0.125f;
  else if (wl < 2048.0f)  inv_s = inv;
  else {
    float smooth = (8192.0f / wl - 1.0f) * (1.0f / 3.0f);
    inv_s = (1.0f - smooth) * 0.125f * inv + smooth * inv;
  }
  float ang = (float)t * inv_s;
  float s, c;
  sincosf(ang, &s, &c);
  if (hh < NH) {
    const float* base = qf + (long)t * HID + hh * HD;
    float lo = base[d], hi = base[d + 64];
    long o = ((long)hh * T + t) * HD;
    qb[o + d]      = f2bf((lo * c - hi * s) * QSCALE);
    qb[o + d + 64] = f2bf((hi * c + lo * s) * QSCALE);
  } else {
    int h = hh - NH;
    const float* base = kf + (long)t * (NKV * HD) + h * HD;
    float lo = base[d], hi = base[d + 64];
    long o = ((long)h * T + t) * HD;
    kb[o + d]      = f2bf(lo * c - hi * s);
    kb[o + d + 64] = f2bf(hi * c + lo * s);
  }
}

// ---------------- V: [t][h*128+d] fp32 -> [h][d][t] bf16 (LDS transpose) ----------------
__global__ __launch_bounds__(256) void transpose_v(const float* __restrict__ vf,
                                                   unsigned short* __restrict__ vtb) {
  __shared__ float tile[64][33];
  int t0 = blockIdx.x * 64, d0 = blockIdx.y * 32, h = blockIdx.z;
  int tid = threadIdx.x;
  int dd = tid & 31, tt = tid >> 5;
#pragma unroll
  for (int i = 0; i < 8; i++) {
    int t = tt + i * 8;
    tile[t][dd] = vf[(long)(t0 + t) * (NKV * HD) + h * HD + d0 + dd];
  }
  __syncthreads();
  int t2 = tid & 63, d2 = tid >> 6;
#pragma unroll
  for (int i = 0; i < 8; i++) {
    int d = d2 + i * 4;
    vtb[((long)(h * HD + d0 + d)) * T + t0 + t2] = f2bf(tile[t2][d]);
  }
}

// ---------------- flash attention, causal, GQA ----------------
// block = (q-tile of 64, head). 4 waves x 16 q-rows. BK=64. Online softmax in regs.
__global__ __launch_bounds__(256) void attn_kernel(const unsigned short* __restrict__ qb,
                                                   const unsigned short* __restrict__ kbuf,
                                                   const unsigned short* __restrict__ vtb,
                                                   unsigned short* __restrict__ ob) {
  __shared__ __align__(16) unsigned short Ks[64][136];   // [key][d]
  __shared__ __align__(16) unsigned short Vs[128][72];   // [d][key] (V^T)
  __shared__ __align__(16) unsigned short Ps[4][16][72]; // per-wave P tile
  int h = blockIdx.y, kvh = h >> 2;
  int q0 = blockIdx.x * 64;
  int tid = threadIdx.x, wave = tid >> 6, lane = tid & 63;
  int lm = lane & 15, q4 = lane >> 4;

  // Q fragments (A-operand layout), persistent in registers
  int qrow = q0 + wave * 16 + lm;
  short8 aq[4];
#pragma unroll
  for (int kk = 0; kk < 4; kk++)
    aq[kk] = *(const short8*)&qb[((long)h * T + qrow) * HD + kk * 32 + q4 * 8];

  f32x4 oacc[8] = {};
  float m_i[4], l_i[4];
#pragma unroll
  for (int r = 0; r < 4; r++) { m_i[r] = -__builtin_inff(); l_i[r] = 0.0f; }

  int ntiles = blockIdx.x + 1;  // causal: only tiles with kb0 <= q0
  for (int tile = 0; tile < ntiles; tile++) {
    int kb0 = tile * 64;
#pragma unroll
    for (int i = 0; i < 4; i++) {
      int t = tid + i * 256;
      { int row = t >> 4, col8 = (t & 15) * 8;   // K: 64 rows x 128 d
        *(short8*)&Ks[row][col8] = *(const short8*)&kbuf[((long)kvh * T + kb0 + row) * HD + col8]; }
      { int row = t >> 3, col8 = (t & 7) * 8;    // V^T: 128 rows x 64 keys
        *(short8*)&Vs[row][col8] = *(const short8*)&vtb[((long)kvh * HD + row) * T + kb0 + col8]; }
    }
    __syncthreads();

    // S = Q K^T (16q x 64k per wave)
    f32x4 sacc[4] = {};
#pragma unroll
    for (int kk = 0; kk < 4; kk++)
#pragma unroll
      for (int j = 0; j < 4; j++) {
        short8 bk = *(const short8*)&Ks[j * 16 + lm][kk * 32 + q4 * 8];
        sacc[j] = __builtin_amdgcn_mfma_f32_16x16x32_bf16(aq[kk], bk, sacc[j], 0, 0, 0);
      }

    // causal mask + row max
    float mx[4] = { -__builtin_inff(), -__builtin_inff(), -__builtin_inff(), -__builtin_inff() };
#pragma unroll
    for (int j = 0; j < 4; j++) {
      int key = kb0 + j * 16 + lm;
#pragma unroll
      for (int r = 0; r < 4; r++) {
        int qg = q0 + wave * 16 + q4 * 4 + r;
        if (key > qg) sacc[j][r] = -__builtin_inff();
        mx[r] = fmaxf(mx[r], sacc[j][r]);
      }
    }
#pragma unroll
    for (int off = 8; off >= 1; off >>= 1)
#pragma unroll
      for (int r = 0; r < 4; r++)
        mx[r] = fmaxf(mx[r], __shfl_xor(mx[r], off, 64));

    float alpha[4], rs[4];
#pragma unroll
    for (int r = 0; r < 4; r++) {
      float mn = fmaxf(m_i[r], mx[r]);
      alpha[r] = (mn > -__builtin_inff()) ? __expf(m_i[r] - mn) : 1.0f;
      m_i[r] = mn;
      rs[r] = 0.0f;
    }
#pragma unroll
    for (int j = 0; j < 4; j++)
#pragma unroll
      for (int r = 0; r < 4; r++) {
        float p = (sacc[j][r] > -__builtin_inff()) ? __expf(sacc[j][r] - m_i[r]) : 0.0f;
        sacc[j][r] = p;
        rs[r] += p;
      }
#pragma unroll
    for (int off = 8; off >= 1; off >>= 1)
#pragma unroll
      for (int r = 0; r < 4; r++)
        rs[r] += __shfl_xor(rs[r], off, 64);
#pragma unroll
    for (int r = 0; r < 4; r++) l_i[r] = l_i[r] * alpha[r] + rs[r];

    // rescale O accumulator
#pragma unroll
    for (int n = 0; n < 8; n++)
#pragma unroll
      for (int r = 0; r < 4; r++) oacc[n][r] *= alpha[r];

    // P: C-layout regs -> LDS (so it can be re-read in A-operand layout)
#pragma unroll
    for (int j = 0; j < 4; j++)
#pragma unroll
      for (int r = 0; r < 4; r++)
        Ps[wave][q4 * 4 + r][j * 16 + lm] = f2bf(sacc[j][r]);

    // O += P V   (V^T in LDS makes B-operand reads contiguous ds_read_b128)
#pragma unroll
    for (int kk2 = 0; kk2 < 2; kk2++) {
      short8 ap = *(const short8*)&Ps[wave][lm][kk2 * 32 + q4 * 8];
#pragma unroll
      for (int n = 0; n < 8; n++) {
        short8 bv = *(const short8*)&Vs[n * 16 + lm][kk2 * 32 + q4 * 8];
        oacc[n] = __builtin_amdgcn_mfma_f32_16x16x32_bf16(ap, bv, oacc[n], 0, 0, 0);
      }
    }
    __syncthreads();
  }

  // epilogue: divide by l, write [t][h*128+d] bf16
#pragma unroll
  for (int r = 0; r < 4; r++) {
    float invl = 1.0f / l_i[r];
    int qg = q0 + wave * 16 + q4 * 4 + r;
#pragma unroll
    for (int n = 0; n < 8; n++)
      ob[(long)qg * HID + h * HD + n * 16 + lm] = f2bf(oacc[n][r] * invl);
  }
}

extern "C" void kernel_launch(void* const* d_in, const int* in_sizes, int n_in,
                              void* d_out, int out_size, void* d_ws, size_t ws_size,
                              hipStream_t stream) {
  const float* x  = (const float*)d_in[0];
  const float* Wq = (const float*)d_in[1];
  const float* Wk = (const float*)d_in[2];
  const float* Wv = (const float*)d_in[3];
  const float* Wo = (const float*)d_in[4];
  float* out = (float*)d_out;

  char* ws = (char*)d_ws;
  size_t off = 0;
  auto alloc = [&](size_t bytes) {
    char* p = ws + off;
    off += (bytes + 255) & ~(size_t)255;
    return p;
  };
  unsigned short* x_bf  = (unsigned short*)alloc((size_t)T * HID * 2);
  unsigned short* wq_bf = (unsigned short*)alloc((size_t)HID * HID * 2);  // later reused for Wo
  unsigned short* wk_bf = (unsigned short*)alloc((size_t)NKV * HD * HID * 2);
  unsigned short* wv_bf = (unsigned short*)alloc((size_t)NKV * HD * HID * 2);
  float* qf = (float*)alloc((size_t)T * HID * 4);
  float* kf = (float*)alloc((size_t)T * NKV * HD * 4);
  float* vf = (float*)alloc((size_t)T * NKV * HD * 4);
  unsigned short* qb  = (unsigned short*)alloc((size_t)NH * T * HD * 2);
  unsigned short* kbb = (unsigned short*)alloc((size_t)NKV * T * HD * 2);
  unsigned short* vtb = (unsigned short*)alloc((size_t)NKV * HD * T * 2);
  unsigned short* obb = (unsigned short*)alloc((size_t)T * HID * 2);

  auto cast = [&](const float* s, unsigned short* d, long n) {
    int n4 = (int)(n / 4);
    cast_bf16_kernel<<<dim3((n4 + 255) / 256), dim3(256), 0, stream>>>(s, d, n4);
  };
  cast(x,  x_bf,  (long)T * HID);
  cast(Wq, wq_bf, (long)HID * HID);
  cast(Wk, wk_bf, (long)NKV * HD * HID);
  cast(Wv, wv_bf, (long)NKV * HD * HID);

  gemm_bt<<<dim3(HID / 128, T / 128), dim3(256), 0, stream>>>(x_bf, wq_bf, qf, T, HID, HID);
  gemm_bt<<<dim3((NKV * HD) / 128, T / 128), dim3(256), 0, stream>>>(x_bf, wk_bf, kf, T, NKV * HD, HID);
  gemm_bt<<<dim3((NKV * HD) / 128, T / 128), dim3(256), 0, stream>>>(x_bf, wv_bf, vf, T, NKV * HD, HID);

  rope_qk<<<dim3(T, NH + NKV), dim3(64), 0, stream>>>(qf, kf, qb, kbb);
  transpose_v<<<dim3(T / 64, HD / 32, NKV), dim3(256), 0, stream>>>(vf, vtb);

  cast(Wo, wq_bf, (long)HID * HID);  // Wq slot no longer needed
  attn_kernel<<<dim3(T / 64, NH), dim3(256), 0, stream>>>(qb, kbb, vtb, obb);
  gemm_bt<<<dim3(HID / 128, T / 128), dim3(256), 0, stream>>>(obb, wq_bf, out, T, HID, HID);
}